// Round 5
// baseline (87.494 us; speedup 1.0000x reference)
//
#include <hip/hip_runtime.h>

// ChannelAttention b=2, n=4096, c=32 fp32.
// S = X X^T (Gram), softmax over j per row i, out[j,c] = sum_i attn[i,j] x[i,c]; out*g + x.
//
// R7 -> R8: model locked by R6/R7 evidence: kernels are AGGREGATE-L2-BW bound
// at ~14 TB/s effective (R6 win == traffic/14TB/s exactly; R7's 2x TLP at
// constant traffic gained nothing). Per-block traffic is constant (each block
// reads xf[b]+xt[b] = 512KB), so: fewer, wider blocks.
//   k1: 64-i tiles, 128 blocks  -> 32 MB L2   (was 64)
//   k2: 64-j tiles, 128 blocks  -> 64 MB L2   (was 128)
// Blocks back to 512 threads / 8 waves (R7's 1024-thread blocks regressed).
// XT stored BLOCK-TRANSPOSED [b][n/32][c][32] so k2's xt loads are contiguous
// 1KB wave bursts (were 16x64B segments) — attacks the 14 vs 34.5 TB/s gap.
//
// MFMA plan (16x16x32 f16, K = c = 32):
//  k0: convert x -> Xf16 [b][n][c] and XT2 f16 [b][n/32][c][32]  (ws)
//  k1: Z_i = sum_j exp(s_ij - 48); store c2[i] = -log2(Z_i) - 48*log2e
//  k2: per 64-j tile: S-MFMA -> attn=exp2(s*log2e + c2[i]) (fp16)
//      -> in-register quad shuffle (8x ds_bpermute + 4x cndmask per 16-j) -> PV-MFMA.

typedef _Float16 half8 __attribute__((ext_vector_type(8)));
typedef _Float16 half4v __attribute__((ext_vector_type(4)));
typedef _Float16 half2v __attribute__((ext_vector_type(2)));
typedef float float4v __attribute__((ext_vector_type(4)));
typedef int int4v __attribute__((ext_vector_type(4)));

#define NN 4096
#define CC 32
#define L2E 1.44269504f
#define SHIFT 48.0f

// ---------------- k0: fp32 -> fp16 row-major + fp16 block-transposed ----------------
__global__ __launch_bounds__(256) void k_convert(const float* __restrict__ x,
                                                 _Float16* __restrict__ xf,
                                                 _Float16* __restrict__ xt) {
    const int t = blockIdx.x * 256 + threadIdx.x;   // 65536 threads
    const int n  = t & 4095;
    const int cg = (t >> 12) & 7;
    const int b  = t >> 15;
    const int row = (b << 12) | n;
    const float4* src = (const float4*)(x + (size_t)row * CC + cg * 4);
    float4 v = *src;
    _Float16 h0 = (_Float16)v.x, h1 = (_Float16)v.y, h2 = (_Float16)v.z, h3 = (_Float16)v.w;
    *(half4v*)(xf + (size_t)row * CC + cg * 4) = (half4v){h0, h1, h2, h3};
    // XT2[b][n>>5][c][n&31]
    _Float16* p = xt + (size_t)b * CC * NN + (size_t)(n >> 5) * (CC * 32) + cg * 4 * 32 + (n & 31);
    p[0]  = h0;
    p[32] = h1;
    p[64] = h2;
    p[96] = h3;
}

// ---------------- k1: per-row shifted sum-of-exp -> c2[i] ----------------
// Block = 512 threads (8 waves), one 64-row i-tile (4 A-frags); each wave covers
// 512 j's: 8 iters x 4 B-tiles, 1-deep prefetch. 128 blocks total.
__global__ __launch_bounds__(512, 2) void k_pass1(const _Float16* __restrict__ xf,
                                                  float* __restrict__ c2out) {
    const int tid = threadIdx.x;
    const int wave = tid >> 6, lane = tid & 63;
    const int quad = lane >> 4, l15 = lane & 15;
    const int b = blockIdx.x >> 6;
    const int i0 = (blockIdx.x & 63) * 64;
    const _Float16* xb = xf + (size_t)b * NN * CC;

    const half8 af0 = *(const half8*)(xb + (size_t)(i0 + l15) * CC + quad * 8);
    const half8 af1 = *(const half8*)(xb + (size_t)(i0 + 16 + l15) * CC + quad * 8);
    const half8 af2 = *(const half8*)(xb + (size_t)(i0 + 32 + l15) * CC + quad * 8);
    const half8 af3 = *(const half8*)(xb + (size_t)(i0 + 48 + l15) * CC + quad * 8);
    const float4v zf = {0.f, 0.f, 0.f, 0.f};
    float z0[4] = {0.f, 0.f, 0.f, 0.f};
    float z1[4] = {0.f, 0.f, 0.f, 0.f};
    float z2[4] = {0.f, 0.f, 0.f, 0.f};
    float z3[4] = {0.f, 0.f, 0.f, 0.f};
    const float c2c = -SHIFT * L2E;

    const int jbase = wave * 512;
    half8 b0 = *(const half8*)(xb + (size_t)(jbase + l15) * CC + quad * 8);
    half8 b1 = *(const half8*)(xb + (size_t)(jbase + 16 + l15) * CC + quad * 8);
    half8 b2 = *(const half8*)(xb + (size_t)(jbase + 32 + l15) * CC + quad * 8);
    half8 b3 = *(const half8*)(xb + (size_t)(jbase + 48 + l15) * CC + quad * 8);

    for (int jt = 0; jt < 8; ++jt) {           // 8 iters x 4 tiles x 16 j = 512 j
        const int jn = jbase + ((jt + 1) & 7) * 64;   // wraps on last iter (harmless)
        half8 n0 = *(const half8*)(xb + (size_t)(jn + l15) * CC + quad * 8);
        half8 n1 = *(const half8*)(xb + (size_t)(jn + 16 + l15) * CC + quad * 8);
        half8 n2 = *(const half8*)(xb + (size_t)(jn + 32 + l15) * CC + quad * 8);
        half8 n3 = *(const half8*)(xb + (size_t)(jn + 48 + l15) * CC + quad * 8);

        // phase A: i-rows i0..i0+31
        {
            float4v s00 = __builtin_amdgcn_mfma_f32_16x16x32_f16(af0, b0, zf, 0, 0, 0);
            float4v s01 = __builtin_amdgcn_mfma_f32_16x16x32_f16(af0, b1, zf, 0, 0, 0);
            float4v s02 = __builtin_amdgcn_mfma_f32_16x16x32_f16(af0, b2, zf, 0, 0, 0);
            float4v s03 = __builtin_amdgcn_mfma_f32_16x16x32_f16(af0, b3, zf, 0, 0, 0);
            float4v s10 = __builtin_amdgcn_mfma_f32_16x16x32_f16(af1, b0, zf, 0, 0, 0);
            float4v s11 = __builtin_amdgcn_mfma_f32_16x16x32_f16(af1, b1, zf, 0, 0, 0);
            float4v s12 = __builtin_amdgcn_mfma_f32_16x16x32_f16(af1, b2, zf, 0, 0, 0);
            float4v s13 = __builtin_amdgcn_mfma_f32_16x16x32_f16(af1, b3, zf, 0, 0, 0);
#pragma unroll
            for (int r = 0; r < 4; ++r) {
                z0[r] += __builtin_amdgcn_exp2f(fmaf(s00[r], L2E, c2c));
                z0[r] += __builtin_amdgcn_exp2f(fmaf(s01[r], L2E, c2c));
                z0[r] += __builtin_amdgcn_exp2f(fmaf(s02[r], L2E, c2c));
                z0[r] += __builtin_amdgcn_exp2f(fmaf(s03[r], L2E, c2c));
                z1[r] += __builtin_amdgcn_exp2f(fmaf(s10[r], L2E, c2c));
                z1[r] += __builtin_amdgcn_exp2f(fmaf(s11[r], L2E, c2c));
                z1[r] += __builtin_amdgcn_exp2f(fmaf(s12[r], L2E, c2c));
                z1[r] += __builtin_amdgcn_exp2f(fmaf(s13[r], L2E, c2c));
            }
        }
        // phase B: i-rows i0+32..i0+63
        {
            float4v s00 = __builtin_amdgcn_mfma_f32_16x16x32_f16(af2, b0, zf, 0, 0, 0);
            float4v s01 = __builtin_amdgcn_mfma_f32_16x16x32_f16(af2, b1, zf, 0, 0, 0);
            float4v s02 = __builtin_amdgcn_mfma_f32_16x16x32_f16(af2, b2, zf, 0, 0, 0);
            float4v s03 = __builtin_amdgcn_mfma_f32_16x16x32_f16(af2, b3, zf, 0, 0, 0);
            float4v s10 = __builtin_amdgcn_mfma_f32_16x16x32_f16(af3, b0, zf, 0, 0, 0);
            float4v s11 = __builtin_amdgcn_mfma_f32_16x16x32_f16(af3, b1, zf, 0, 0, 0);
            float4v s12 = __builtin_amdgcn_mfma_f32_16x16x32_f16(af3, b2, zf, 0, 0, 0);
            float4v s13 = __builtin_amdgcn_mfma_f32_16x16x32_f16(af3, b3, zf, 0, 0, 0);
#pragma unroll
            for (int r = 0; r < 4; ++r) {
                z2[r] += __builtin_amdgcn_exp2f(fmaf(s00[r], L2E, c2c));
                z2[r] += __builtin_amdgcn_exp2f(fmaf(s01[r], L2E, c2c));
                z2[r] += __builtin_amdgcn_exp2f(fmaf(s02[r], L2E, c2c));
                z2[r] += __builtin_amdgcn_exp2f(fmaf(s03[r], L2E, c2c));
                z3[r] += __builtin_amdgcn_exp2f(fmaf(s10[r], L2E, c2c));
                z3[r] += __builtin_amdgcn_exp2f(fmaf(s11[r], L2E, c2c));
                z3[r] += __builtin_amdgcn_exp2f(fmaf(s12[r], L2E, c2c));
                z3[r] += __builtin_amdgcn_exp2f(fmaf(s13[r], L2E, c2c));
            }
        }
        b0 = n0; b1 = n1; b2 = n2; b3 = n3;
    }
    // combine over the 16 j-lanes within each quad group
#pragma unroll
    for (int off = 1; off <= 8; off <<= 1) {
#pragma unroll
        for (int r = 0; r < 4; ++r) {
            z0[r] += __shfl_xor(z0[r], off, 64);
            z1[r] += __shfl_xor(z1[r], off, 64);
            z2[r] += __shfl_xor(z2[r], off, 64);
            z3[r] += __shfl_xor(z3[r], off, 64);
        }
    }
    __shared__ float zw[8][64];
    if (l15 == 0) {
#pragma unroll
        for (int r = 0; r < 4; ++r) {
            zw[wave][quad * 4 + r]      = z0[r];
            zw[wave][16 + quad * 4 + r] = z1[r];
            zw[wave][32 + quad * 4 + r] = z2[r];
            zw[wave][48 + quad * 4 + r] = z3[r];
        }
    }
    __syncthreads();
    if (tid < 64) {
        float zs = 0.f;
#pragma unroll
        for (int w = 0; w < 8; ++w) zs += zw[w][tid];
        c2out[b * NN + i0 + tid] = -(__builtin_amdgcn_logf(zs) + SHIFT * L2E);
    }
}

// ---------------- k2: output pass ----------------
// Block = 512 threads (8 waves), one 64-j tile (4 B-frags); wave w covers i in
// [w*512,(w+1)*512): 16 iters x 32 i. 128 blocks total. Two phases per iter
// (j-subtiles 0,1 then 2,3) to cap register pressure.
__global__ __launch_bounds__(512, 2) void k_pass2(const _Float16* __restrict__ xf,
                                                  const _Float16* __restrict__ xt,
                                                  const float* __restrict__ c2,
                                                  const float* __restrict__ x,
                                                  const float* __restrict__ gamma,
                                                  float* __restrict__ out) {
    const int tid = threadIdx.x;
    const int wave = tid >> 6, lane = tid & 63;
    const int quad = lane >> 4, l15 = lane & 15;
    const int b = blockIdx.x >> 6;
    const int j0 = (blockIdx.x & 63) * 64;
    const _Float16* xb  = xf + (size_t)b * NN * CC;
    const _Float16* xtb = xt + (size_t)b * CC * NN;   // XT2 layout [n/32][c][32]
    const float* c2b = c2 + b * NN;

    __shared__ float red[8][64][32];   // 64 KB

    // bpermute byte addresses: A0/A1 pull from lane ((q&1)*32 + j15),
    // A2/A3 from lane ((q&1)*32 + 16 + j15). Select p0 (q<2) vs p1 (q>=2) data.
    const int addrLo = (((quad & 1) << 5) + l15) << 2;
    const int addrHi = addrLo + 64;
    const bool lo32 = (lane < 32);

    const half8 bj0 = *(const half8*)(xb + (size_t)(j0 + l15) * CC + quad * 8);
    const half8 bj1 = *(const half8*)(xb + (size_t)(j0 + 16 + l15) * CC + quad * 8);
    const half8 bj2 = *(const half8*)(xb + (size_t)(j0 + 32 + l15) * CC + quad * 8);
    const half8 bj3 = *(const half8*)(xb + (size_t)(j0 + 48 + l15) * CC + quad * 8);
    const float4v zf = {0.f, 0.f, 0.f, 0.f};
    float4v acc00 = zf, acc01 = zf, acc10 = zf, acc11 = zf;
    float4v acc20 = zf, acc21 = zf, acc30 = zf, acc31 = zf;

    const int ibase = wave * 512;
    half8 a0  = *(const half8*)(xb + (size_t)(ibase + l15) * CC + quad * 8);
    half8 a1  = *(const half8*)(xb + (size_t)(ibase + 16 + l15) * CC + quad * 8);
    // XT2: i-block of 32 -> contiguous [c][32]; c=l15 row, cols quad*8..+8
    half8 xb0 = *(const half8*)(xtb + (size_t)ibase * 32 + l15 * 32 + quad * 8);
    half8 xb1 = *(const half8*)(xtb + (size_t)ibase * 32 + 512 + l15 * 32 + quad * 8);
    float4v c20 = *(const float4v*)(c2b + ibase + quad * 4);
    float4v c21 = *(const float4v*)(c2b + ibase + 16 + quad * 4);

    for (int it = 0; it < 16; ++it) {
        const int inx = ibase + ((it + 1) & 15) * 32;   // wraps on last iter
        half8 na0  = *(const half8*)(xb + (size_t)(inx + l15) * CC + quad * 8);
        half8 na1  = *(const half8*)(xb + (size_t)(inx + 16 + l15) * CC + quad * 8);
        half8 nxb0 = *(const half8*)(xtb + (size_t)inx * 32 + l15 * 32 + quad * 8);
        half8 nxb1 = *(const half8*)(xtb + (size_t)inx * 32 + 512 + l15 * 32 + quad * 8);
        float4v nc20 = *(const float4v*)(c2b + inx + quad * 4);
        float4v nc21 = *(const float4v*)(c2b + inx + 16 + quad * 4);

        // ---- phase A: j-subtiles 0,1 ----
        {
            float4v s00 = __builtin_amdgcn_mfma_f32_16x16x32_f16(a0, bj0, zf, 0, 0, 0);
            float4v s10 = __builtin_amdgcn_mfma_f32_16x16x32_f16(a1, bj0, zf, 0, 0, 0);
            float4v s01 = __builtin_amdgcn_mfma_f32_16x16x32_f16(a0, bj1, zf, 0, 0, 0);
            float4v s11 = __builtin_amdgcn_mfma_f32_16x16x32_f16(a1, bj1, zf, 0, 0, 0);
            float4v e00, e10, e01, e11;
#pragma unroll
            for (int r = 0; r < 4; ++r) {
                e00[r] = __builtin_amdgcn_exp2f(fmaf(s00[r], L2E, c20[r]));
                e10[r] = __builtin_amdgcn_exp2f(fmaf(s10[r], L2E, c21[r]));
                e01[r] = __builtin_amdgcn_exp2f(fmaf(s01[r], L2E, c20[r]));
                e11[r] = __builtin_amdgcn_exp2f(fmaf(s11[r], L2E, c21[r]));
            }
            {
                const int d0 = __builtin_bit_cast(int, (half2v)__builtin_amdgcn_cvt_pkrtz(e00[0], e00[1]));
                const int d1 = __builtin_bit_cast(int, (half2v)__builtin_amdgcn_cvt_pkrtz(e00[2], e00[3]));
                const int d2 = __builtin_bit_cast(int, (half2v)__builtin_amdgcn_cvt_pkrtz(e10[0], e10[1]));
                const int d3 = __builtin_bit_cast(int, (half2v)__builtin_amdgcn_cvt_pkrtz(e10[2], e10[3]));
                const int q0 = __builtin_amdgcn_ds_bpermute(addrLo, d0);
                const int q1 = __builtin_amdgcn_ds_bpermute(addrLo, d1);
                const int q2 = __builtin_amdgcn_ds_bpermute(addrHi, d0);
                const int q3 = __builtin_amdgcn_ds_bpermute(addrHi, d1);
                const int q4 = __builtin_amdgcn_ds_bpermute(addrLo, d2);
                const int q5 = __builtin_amdgcn_ds_bpermute(addrLo, d3);
                const int q6 = __builtin_amdgcn_ds_bpermute(addrHi, d2);
                const int q7 = __builtin_amdgcn_ds_bpermute(addrHi, d3);
                int4v ai;
                ai[0] = lo32 ? q0 : q4;
                ai[1] = lo32 ? q1 : q5;
                ai[2] = lo32 ? q2 : q6;
                ai[3] = lo32 ? q3 : q7;
                const half8 a2 = __builtin_bit_cast(half8, ai);   // P^T[j=j0+l15][i32]
                acc00 = __builtin_amdgcn_mfma_f32_16x16x32_f16(a2, xb0, acc00, 0, 0, 0);
                acc01 = __builtin_amdgcn_mfma_f32_16x16x32_f16(a2, xb1, acc01, 0, 0, 0);
            }
            {
                const int d0 = __builtin_bit_cast(int, (half2v)__builtin_amdgcn_cvt_pkrtz(e01[0], e01[1]));
                const int d1 = __builtin_bit_cast(int, (half2v)__builtin_amdgcn_cvt_pkrtz(e01[2], e01[3]));
                const int d2 = __builtin_bit_cast(int, (half2v)__builtin_amdgcn_cvt_pkrtz(e11[0], e11[1]));
                const int d3 = __builtin_bit_cast(int, (half2v)__builtin_amdgcn_cvt_pkrtz(e11[2], e11[3]));
                const int q0 = __builtin_amdgcn_ds_bpermute(addrLo, d0);
                const int q1 = __builtin_amdgcn_ds_bpermute(addrLo, d1);
                const int q2 = __builtin_amdgcn_ds_bpermute(addrHi, d0);
                const int q3 = __builtin_amdgcn_ds_bpermute(addrHi, d1);
                const int q4 = __builtin_amdgcn_ds_bpermute(addrLo, d2);
                const int q5 = __builtin_amdgcn_ds_bpermute(addrLo, d3);
                const int q6 = __builtin_amdgcn_ds_bpermute(addrHi, d2);
                const int q7 = __builtin_amdgcn_ds_bpermute(addrHi, d3);
                int4v ai;
                ai[0] = lo32 ? q0 : q4;
                ai[1] = lo32 ? q1 : q5;
                ai[2] = lo32 ? q2 : q6;
                ai[3] = lo32 ? q3 : q7;
                const half8 a2 = __builtin_bit_cast(half8, ai);   // P^T[j=j0+16+l15][i32]
                acc10 = __builtin_amdgcn_mfma_f32_16x16x32_f16(a2, xb0, acc10, 0, 0, 0);
                acc11 = __builtin_amdgcn_mfma_f32_16x16x32_f16(a2, xb1, acc11, 0, 0, 0);
            }
        }
        // ---- phase B: j-subtiles 2,3 ----
        {
            float4v s00 = __builtin_amdgcn_mfma_f32_16x16x32_f16(a0, bj2, zf, 0, 0, 0);
            float4v s10 = __builtin_amdgcn_mfma_f32_16x16x32_f16(a1, bj2, zf, 0, 0, 0);
            float4v s01 = __builtin_amdgcn_mfma_f32_16x16x32_f16(a0, bj3, zf, 0, 0, 0);
            float4v s11 = __builtin_amdgcn_mfma_f32_16x16x32_f16(a1, bj3, zf, 0, 0, 0);
            float4v e00, e10, e01, e11;
#pragma unroll
            for (int r = 0; r < 4; ++r) {
                e00[r] = __builtin_amdgcn_exp2f(fmaf(s00[r], L2E, c20[r]));
                e10[r] = __builtin_amdgcn_exp2f(fmaf(s10[r], L2E, c21[r]));
                e01[r] = __builtin_amdgcn_exp2f(fmaf(s01[r], L2E, c20[r]));
                e11[r] = __builtin_amdgcn_exp2f(fmaf(s11[r], L2E, c21[r]));
            }
            {
                const int d0 = __builtin_bit_cast(int, (half2v)__builtin_amdgcn_cvt_pkrtz(e00[0], e00[1]));
                const int d1 = __builtin_bit_cast(int, (half2v)__builtin_amdgcn_cvt_pkrtz(e00[2], e00[3]));
                const int d2 = __builtin_bit_cast(int, (half2v)__builtin_amdgcn_cvt_pkrtz(e10[0], e10[1]));
                const int d3 = __builtin_bit_cast(int, (half2v)__builtin_amdgcn_cvt_pkrtz(e10[2], e10[3]));
                const int q0 = __builtin_amdgcn_ds_bpermute(addrLo, d0);
                const int q1 = __builtin_amdgcn_ds_bpermute(addrLo, d1);
                const int q2 = __builtin_amdgcn_ds_bpermute(addrHi, d0);
                const int q3 = __builtin_amdgcn_ds_bpermute(addrHi, d1);
                const int q4 = __builtin_amdgcn_ds_bpermute(addrLo, d2);
                const int q5 = __builtin_amdgcn_ds_bpermute(addrLo, d3);
                const int q6 = __builtin_amdgcn_ds_bpermute(addrHi, d2);
                const int q7 = __builtin_amdgcn_ds_bpermute(addrHi, d3);
                int4v ai;
                ai[0] = lo32 ? q0 : q4;
                ai[1] = lo32 ? q1 : q5;
                ai[2] = lo32 ? q2 : q6;
                ai[3] = lo32 ? q3 : q7;
                const half8 a2 = __builtin_bit_cast(half8, ai);   // P^T[j=j0+32+l15][i32]
                acc20 = __builtin_amdgcn_mfma_f32_16x16x32_f16(a2, xb0, acc20, 0, 0, 0);
                acc21 = __builtin_amdgcn_mfma_f32_16x16x32_f16(a2, xb1, acc21, 0, 0, 0);
            }
            {
                const int d0 = __builtin_bit_cast(int, (half2v)__builtin_amdgcn_cvt_pkrtz(e01[0], e01[1]));
                const int d1 = __builtin_bit_cast(int, (half2v)__builtin_amdgcn_cvt_pkrtz(e01[2], e01[3]));
                const int d2 = __builtin_bit_cast(int, (half2v)__builtin_amdgcn_cvt_pkrtz(e11[0], e11[1]));
                const int d3 = __builtin_bit_cast(int, (half2v)__builtin_amdgcn_cvt_pkrtz(e11[2], e11[3]));
                const int q0 = __builtin_amdgcn_ds_bpermute(addrLo, d0);
                const int q1 = __builtin_amdgcn_ds_bpermute(addrLo, d1);
                const int q2 = __builtin_amdgcn_ds_bpermute(addrHi, d0);
                const int q3 = __builtin_amdgcn_ds_bpermute(addrHi, d1);
                const int q4 = __builtin_amdgcn_ds_bpermute(addrLo, d2);
                const int q5 = __builtin_amdgcn_ds_bpermute(addrLo, d3);
                const int q6 = __builtin_amdgcn_ds_bpermute(addrHi, d2);
                const int q7 = __builtin_amdgcn_ds_bpermute(addrHi, d3);
                int4v ai;
                ai[0] = lo32 ? q0 : q4;
                ai[1] = lo32 ? q1 : q5;
                ai[2] = lo32 ? q2 : q6;
                ai[3] = lo32 ? q3 : q7;
                const half8 a2 = __builtin_bit_cast(half8, ai);   // P^T[j=j0+48+l15][i32]
                acc30 = __builtin_amdgcn_mfma_f32_16x16x32_f16(a2, xb0, acc30, 0, 0, 0);
                acc31 = __builtin_amdgcn_mfma_f32_16x16x32_f16(a2, xb1, acc31, 0, 0, 0);
            }
        }

        a0 = na0; a1 = na1; xb0 = nxb0; xb1 = nxb1; c20 = nc20; c21 = nc21;
    }

    // block reduction across the 8 waves
#pragma unroll
    for (int r = 0; r < 4; ++r) {
        red[wave][quad * 4 + r][l15]           = acc00[r];
        red[wave][quad * 4 + r][l15 + 16]      = acc01[r];
        red[wave][16 + quad * 4 + r][l15]      = acc10[r];
        red[wave][16 + quad * 4 + r][l15 + 16] = acc11[r];
        red[wave][32 + quad * 4 + r][l15]      = acc20[r];
        red[wave][32 + quad * 4 + r][l15 + 16] = acc21[r];
        red[wave][48 + quad * 4 + r][l15]      = acc30[r];
        red[wave][48 + quad * 4 + r][l15 + 16] = acc31[r];
    }
    __syncthreads();
    {
        const int jj = tid >> 5, c = tid & 31;   // 512 threads: 16 j x 32 c, x4
        const float g = gamma[0];
#pragma unroll
        for (int h = 0; h < 4; ++h) {
            const int j = jj + h * 16;
            float s = 0.f;
#pragma unroll
            for (int w = 0; w < 8; ++w) s += red[w][j][c];
            const size_t o = (size_t)(b * NN + j0 + j) * CC + c;
            out[o] = fmaf(g, s, x[o]);
        }
    }
}

extern "C" void kernel_launch(void* const* d_in, const int* in_sizes, int n_in,
                              void* d_out, int out_size, void* d_ws, size_t ws_size,
                              hipStream_t stream) {
    const float* x     = (const float*)d_in[0];
    const float* gamma = (const float*)d_in[1];
    float* out = (float*)d_out;

    // ws layout: Xf16 (512 KB) | XT2 f16 (512 KB) | c2 fp32 (32 KB)
    _Float16* xf = (_Float16*)d_ws;
    _Float16* xt = xf + (size_t)2 * NN * CC;
    float*    c2 = (float*)(xt + (size_t)2 * CC * NN);

    k_convert<<<dim3(256), dim3(256), 0, stream>>>(x, xf, xt);
    k_pass1 <<<dim3(128), dim3(512), 0, stream>>>(xf, c2);
    k_pass2 <<<dim3(128), dim3(512), 0, stream>>>(xf, xt, c2, x, gamma, out);
}

// Round 6
// 84.590 us; speedup vs baseline: 1.0343x; 1.0343x over previous
//
#include <hip/hip_runtime.h>

// ChannelAttention b=2, n=4096, c=32 fp32.
// S = X X^T (Gram), softmax over j per row i, out[j,c] = sum_i attn[i,j] x[i,c]; out*g + x.
//
// R8 -> R9: R8 regressed (+7.9) -> model update: effective ~14 TB/s L2 BW needs
// ALL 256 CUs consuming (128-block config idled half the chip; R7 showed extra
// waves/CU don't raise per-CU ingest). Lock structure at 256 blocks x 512 thr
// (R6 = best, 79.6us) and cut traffic at constant block count:
//   k1 goes 2D: 256 blocks = 2b x 8 i-tiles(512) x 16 j-tiles(256).
//   Per block: 512 i-rows (32KB) + 256 j-rows (16KB, L1-shared by the 8 waves)
//   = 48KB -> 12 MB total (was 64 MB). Partial Z summed via global atomicAdd
//   into a zeroed buffer (zeroed for free in k0; 16 partials per Z[i]).
//   k2 computes c2 = -(log2(Z) + 48*log2e) on the fly (8 v_log per iter).
// k0/k2 otherwise EXACTLY R6 (orig XT [b][c][n] layout, 32-j tiles, bpermute
// in-register C->A transpose).

typedef _Float16 half8 __attribute__((ext_vector_type(8)));
typedef _Float16 half4v __attribute__((ext_vector_type(4)));
typedef _Float16 half2v __attribute__((ext_vector_type(2)));
typedef float float4v __attribute__((ext_vector_type(4)));
typedef int int4v __attribute__((ext_vector_type(4)));

#define NN 4096
#define CC 32
#define L2E 1.44269504f
#define SHIFT 48.0f

// ---------------- k0: fp32 -> fp16 row-major + fp16 transposed + Z zero ----------------
__global__ __launch_bounds__(256) void k_convert(const float* __restrict__ x,
                                                 _Float16* __restrict__ xf,
                                                 _Float16* __restrict__ xt,
                                                 float* __restrict__ zbuf) {
    const int t = blockIdx.x * 256 + threadIdx.x;   // 65536 threads
    const int n  = t & 4095;
    const int cg = (t >> 12) & 7;
    const int b  = t >> 15;
    const int row = (b << 12) | n;
    const float4* src = (const float4*)(x + (size_t)row * CC + cg * 4);
    float4 v = *src;
    _Float16 h0 = (_Float16)v.x, h1 = (_Float16)v.y, h2 = (_Float16)v.z, h3 = (_Float16)v.w;
    *(half4v*)(xf + (size_t)row * CC + cg * 4) = (half4v){h0, h1, h2, h3};
    _Float16* xtb = xt + (size_t)b * CC * NN;
    xtb[(cg * 4 + 0) * NN + n] = h0;   // consecutive lanes -> consecutive n: coalesced
    xtb[(cg * 4 + 1) * NN + n] = h1;
    xtb[(cg * 4 + 2) * NN + n] = h2;
    xtb[(cg * 4 + 3) * NN + n] = h3;
    if (t < 2 * NN) zbuf[t] = 0.f;     // zero the Z accumulator for k1's atomics
}

// ---------------- k1: 2D-tiled partial sum-of-exp -> atomicAdd Z[i] ----------------
// 256 blocks: b = blk>>7; i-tile = (blk&127)>>4 (512 i), j-tile = blk&15 (256 j).
// 8 waves split i (64 rows each: 4 A-frags, phased 2+2); each wave sweeps all
// 256 j (4 iters x 4 B-tiles, 1-deep prefetch; j-rows L1-shared across waves).
__global__ __launch_bounds__(512, 2) void k_pass1(const _Float16* __restrict__ xf,
                                                  float* __restrict__ zbuf) {
    const int tid = threadIdx.x;
    const int wave = tid >> 6, lane = tid & 63;
    const int quad = lane >> 4, l15 = lane & 15;
    const int b = blockIdx.x >> 7;
    const int r7 = blockIdx.x & 127;
    const int I0 = (r7 >> 4) * 512;
    const int J0 = (r7 & 15) * 256;
    const _Float16* xb = xf + (size_t)b * NN * CC;
    float* zb = zbuf + b * NN;

    const int ib = I0 + wave * 64;
    const half8 af0 = *(const half8*)(xb + (size_t)(ib + l15) * CC + quad * 8);
    const half8 af1 = *(const half8*)(xb + (size_t)(ib + 16 + l15) * CC + quad * 8);
    const half8 af2 = *(const half8*)(xb + (size_t)(ib + 32 + l15) * CC + quad * 8);
    const half8 af3 = *(const half8*)(xb + (size_t)(ib + 48 + l15) * CC + quad * 8);
    const float4v zf = {0.f, 0.f, 0.f, 0.f};
    float z0[4] = {0.f, 0.f, 0.f, 0.f};
    float z1[4] = {0.f, 0.f, 0.f, 0.f};
    float z2[4] = {0.f, 0.f, 0.f, 0.f};
    float z3[4] = {0.f, 0.f, 0.f, 0.f};
    const float c2c = -SHIFT * L2E;

    half8 b0 = *(const half8*)(xb + (size_t)(J0 + l15) * CC + quad * 8);
    half8 b1 = *(const half8*)(xb + (size_t)(J0 + 16 + l15) * CC + quad * 8);
    half8 b2 = *(const half8*)(xb + (size_t)(J0 + 32 + l15) * CC + quad * 8);
    half8 b3 = *(const half8*)(xb + (size_t)(J0 + 48 + l15) * CC + quad * 8);

    for (int jt = 0; jt < 4; ++jt) {           // 4 iters x 4 tiles x 16 j = 256 j
        const int jn = J0 + ((jt + 1) & 3) * 64;   // wraps on last iter (harmless)
        half8 n0 = *(const half8*)(xb + (size_t)(jn + l15) * CC + quad * 8);
        half8 n1 = *(const half8*)(xb + (size_t)(jn + 16 + l15) * CC + quad * 8);
        half8 n2 = *(const half8*)(xb + (size_t)(jn + 32 + l15) * CC + quad * 8);
        half8 n3 = *(const half8*)(xb + (size_t)(jn + 48 + l15) * CC + quad * 8);

        // phase A: i-rows ib..ib+31
        {
            float4v s00 = __builtin_amdgcn_mfma_f32_16x16x32_f16(af0, b0, zf, 0, 0, 0);
            float4v s01 = __builtin_amdgcn_mfma_f32_16x16x32_f16(af0, b1, zf, 0, 0, 0);
            float4v s02 = __builtin_amdgcn_mfma_f32_16x16x32_f16(af0, b2, zf, 0, 0, 0);
            float4v s03 = __builtin_amdgcn_mfma_f32_16x16x32_f16(af0, b3, zf, 0, 0, 0);
            float4v s10 = __builtin_amdgcn_mfma_f32_16x16x32_f16(af1, b0, zf, 0, 0, 0);
            float4v s11 = __builtin_amdgcn_mfma_f32_16x16x32_f16(af1, b1, zf, 0, 0, 0);
            float4v s12 = __builtin_amdgcn_mfma_f32_16x16x32_f16(af1, b2, zf, 0, 0, 0);
            float4v s13 = __builtin_amdgcn_mfma_f32_16x16x32_f16(af1, b3, zf, 0, 0, 0);
#pragma unroll
            for (int r = 0; r < 4; ++r) {
                z0[r] += __builtin_amdgcn_exp2f(fmaf(s00[r], L2E, c2c));
                z0[r] += __builtin_amdgcn_exp2f(fmaf(s01[r], L2E, c2c));
                z0[r] += __builtin_amdgcn_exp2f(fmaf(s02[r], L2E, c2c));
                z0[r] += __builtin_amdgcn_exp2f(fmaf(s03[r], L2E, c2c));
                z1[r] += __builtin_amdgcn_exp2f(fmaf(s10[r], L2E, c2c));
                z1[r] += __builtin_amdgcn_exp2f(fmaf(s11[r], L2E, c2c));
                z1[r] += __builtin_amdgcn_exp2f(fmaf(s12[r], L2E, c2c));
                z1[r] += __builtin_amdgcn_exp2f(fmaf(s13[r], L2E, c2c));
            }
        }
        // phase B: i-rows ib+32..ib+63
        {
            float4v s00 = __builtin_amdgcn_mfma_f32_16x16x32_f16(af2, b0, zf, 0, 0, 0);
            float4v s01 = __builtin_amdgcn_mfma_f32_16x16x32_f16(af2, b1, zf, 0, 0, 0);
            float4v s02 = __builtin_amdgcn_mfma_f32_16x16x32_f16(af2, b2, zf, 0, 0, 0);
            float4v s03 = __builtin_amdgcn_mfma_f32_16x16x32_f16(af2, b3, zf, 0, 0, 0);
            float4v s10 = __builtin_amdgcn_mfma_f32_16x16x32_f16(af3, b0, zf, 0, 0, 0);
            float4v s11 = __builtin_amdgcn_mfma_f32_16x16x32_f16(af3, b1, zf, 0, 0, 0);
            float4v s12 = __builtin_amdgcn_mfma_f32_16x16x32_f16(af3, b2, zf, 0, 0, 0);
            float4v s13 = __builtin_amdgcn_mfma_f32_16x16x32_f16(af3, b3, zf, 0, 0, 0);
#pragma unroll
            for (int r = 0; r < 4; ++r) {
                z2[r] += __builtin_amdgcn_exp2f(fmaf(s00[r], L2E, c2c));
                z2[r] += __builtin_amdgcn_exp2f(fmaf(s01[r], L2E, c2c));
                z2[r] += __builtin_amdgcn_exp2f(fmaf(s02[r], L2E, c2c));
                z2[r] += __builtin_amdgcn_exp2f(fmaf(s03[r], L2E, c2c));
                z3[r] += __builtin_amdgcn_exp2f(fmaf(s10[r], L2E, c2c));
                z3[r] += __builtin_amdgcn_exp2f(fmaf(s11[r], L2E, c2c));
                z3[r] += __builtin_amdgcn_exp2f(fmaf(s12[r], L2E, c2c));
                z3[r] += __builtin_amdgcn_exp2f(fmaf(s13[r], L2E, c2c));
            }
        }
        b0 = n0; b1 = n1; b2 = n2; b3 = n3;
    }
    // combine over the 16 j-lanes within each quad group
#pragma unroll
    for (int off = 1; off <= 8; off <<= 1) {
#pragma unroll
        for (int r = 0; r < 4; ++r) {
            z0[r] += __shfl_xor(z0[r], off, 64);
            z1[r] += __shfl_xor(z1[r], off, 64);
            z2[r] += __shfl_xor(z2[r], off, 64);
            z3[r] += __shfl_xor(z3[r], off, 64);
        }
    }
    // one partial per i-row from this block's j-slice
    if (l15 == 0) {
#pragma unroll
        for (int r = 0; r < 4; ++r) {
            atomicAdd(&zb[ib + quad * 4 + r],      z0[r]);
            atomicAdd(&zb[ib + 16 + quad * 4 + r], z1[r]);
            atomicAdd(&zb[ib + 32 + quad * 4 + r], z2[r]);
            atomicAdd(&zb[ib + 48 + quad * 4 + r], z3[r]);
        }
    }
}

// ---------------- k2: output pass ----------------
// Block = 512 threads (8 waves), one 32-j tile (2 B-frags); wave w covers i in
// [w*512,(w+1)*512), 32 i per iteration (16 iters). 256 blocks total.
// c2 computed on the fly from Z: c2 = -(log2(Z) + 48*log2e).
// C->A transpose in registers per 16-j subtile: 8x ds_bpermute + 4x cndmask.
__global__ __launch_bounds__(512, 2) void k_pass2(const _Float16* __restrict__ xf,
                                                  const _Float16* __restrict__ xt,
                                                  const float* __restrict__ zbuf,
                                                  const float* __restrict__ x,
                                                  const float* __restrict__ gamma,
                                                  float* __restrict__ out) {
    const int tid = threadIdx.x;
    const int wave = tid >> 6, lane = tid & 63;
    const int quad = lane >> 4, l15 = lane & 15;
    const int b = blockIdx.x >> 7;
    const int j0 = (blockIdx.x & 127) * 32;
    const _Float16* xb  = xf + (size_t)b * NN * CC;
    const _Float16* xtb = xt + (size_t)b * CC * NN;
    const float* zb = zbuf + b * NN;

    __shared__ float red[8][32][32];

    // bpermute byte addresses: A0/A1 pull from lane ((q&1)*32 + j15),
    // A2/A3 from lane ((q&1)*32 + 16 + j15). Select p0 (q<2) vs p1 (q>=2) data.
    const int addrLo = (((quad & 1) << 5) + l15) << 2;
    const int addrHi = addrLo + 64;
    const bool lo32 = (lane < 32);

    const half8 bj0 = *(const half8*)(xb + (size_t)(j0 + l15) * CC + quad * 8);
    const half8 bj1 = *(const half8*)(xb + (size_t)(j0 + 16 + l15) * CC + quad * 8);
    const float4v zf = {0.f, 0.f, 0.f, 0.f};
    float4v acc00 = zf, acc01 = zf, acc10 = zf, acc11 = zf;

    const int ibase = wave * 512;
    half8 a0  = *(const half8*)(xb + (size_t)(ibase + l15) * CC + quad * 8);
    half8 a1  = *(const half8*)(xb + (size_t)(ibase + 16 + l15) * CC + quad * 8);
    half8 xb0 = *(const half8*)(xtb + (size_t)l15 * NN + ibase + quad * 8);
    half8 xb1 = *(const half8*)(xtb + (size_t)(l15 + 16) * NN + ibase + quad * 8);
    float4v c20, c21;
    {
        float4v zz0 = *(const float4v*)(zb + ibase + quad * 4);
        float4v zz1 = *(const float4v*)(zb + ibase + 16 + quad * 4);
#pragma unroll
        for (int r = 0; r < 4; ++r) {
            c20[r] = -(__builtin_amdgcn_logf(zz0[r]) + SHIFT * L2E);
            c21[r] = -(__builtin_amdgcn_logf(zz1[r]) + SHIFT * L2E);
        }
    }

    for (int it = 0; it < 16; ++it) {
        const int inx = ibase + ((it + 1) & 15) * 32;   // wraps on last iter
        half8 na0  = *(const half8*)(xb + (size_t)(inx + l15) * CC + quad * 8);
        half8 na1  = *(const half8*)(xb + (size_t)(inx + 16 + l15) * CC + quad * 8);
        half8 nxb0 = *(const half8*)(xtb + (size_t)l15 * NN + inx + quad * 8);
        half8 nxb1 = *(const half8*)(xtb + (size_t)(l15 + 16) * NN + inx + quad * 8);
        float4v nzz0 = *(const float4v*)(zb + inx + quad * 4);
        float4v nzz1 = *(const float4v*)(zb + inx + 16 + quad * 4);

        float4v s00 = __builtin_amdgcn_mfma_f32_16x16x32_f16(a0, bj0, zf, 0, 0, 0);
        float4v s10 = __builtin_amdgcn_mfma_f32_16x16x32_f16(a1, bj0, zf, 0, 0, 0);
        float4v s01 = __builtin_amdgcn_mfma_f32_16x16x32_f16(a0, bj1, zf, 0, 0, 0);
        float4v s11 = __builtin_amdgcn_mfma_f32_16x16x32_f16(a1, bj1, zf, 0, 0, 0);
        float4v e00, e10, e01, e11;
#pragma unroll
        for (int r = 0; r < 4; ++r) {
            e00[r] = __builtin_amdgcn_exp2f(fmaf(s00[r], L2E, c20[r]));
            e10[r] = __builtin_amdgcn_exp2f(fmaf(s10[r], L2E, c21[r]));
            e01[r] = __builtin_amdgcn_exp2f(fmaf(s01[r], L2E, c20[r]));
            e11[r] = __builtin_amdgcn_exp2f(fmaf(s11[r], L2E, c21[r]));
        }
        // ---- subtile 0 (j = j0..j0+15) transpose ----
        {
            const int d0 = __builtin_bit_cast(int, (half2v)__builtin_amdgcn_cvt_pkrtz(e00[0], e00[1]));
            const int d1 = __builtin_bit_cast(int, (half2v)__builtin_amdgcn_cvt_pkrtz(e00[2], e00[3]));
            const int d2 = __builtin_bit_cast(int, (half2v)__builtin_amdgcn_cvt_pkrtz(e10[0], e10[1]));
            const int d3 = __builtin_bit_cast(int, (half2v)__builtin_amdgcn_cvt_pkrtz(e10[2], e10[3]));
            const int q0 = __builtin_amdgcn_ds_bpermute(addrLo, d0);
            const int q1 = __builtin_amdgcn_ds_bpermute(addrLo, d1);
            const int q2 = __builtin_amdgcn_ds_bpermute(addrHi, d0);
            const int q3 = __builtin_amdgcn_ds_bpermute(addrHi, d1);
            const int q4 = __builtin_amdgcn_ds_bpermute(addrLo, d2);
            const int q5 = __builtin_amdgcn_ds_bpermute(addrLo, d3);
            const int q6 = __builtin_amdgcn_ds_bpermute(addrHi, d2);
            const int q7 = __builtin_amdgcn_ds_bpermute(addrHi, d3);
            int4v ai;
            ai[0] = lo32 ? q0 : q4;
            ai[1] = lo32 ? q1 : q5;
            ai[2] = lo32 ? q2 : q6;
            ai[3] = lo32 ? q3 : q7;
            const half8 a2 = __builtin_bit_cast(half8, ai);   // P^T[j=j0+l15][i32]
            acc00 = __builtin_amdgcn_mfma_f32_16x16x32_f16(a2, xb0, acc00, 0, 0, 0);
            acc01 = __builtin_amdgcn_mfma_f32_16x16x32_f16(a2, xb1, acc01, 0, 0, 0);
        }
        // ---- subtile 1 (j = j0+16..j0+31) transpose ----
        {
            const int d0 = __builtin_bit_cast(int, (half2v)__builtin_amdgcn_cvt_pkrtz(e01[0], e01[1]));
            const int d1 = __builtin_bit_cast(int, (half2v)__builtin_amdgcn_cvt_pkrtz(e01[2], e01[3]));
            const int d2 = __builtin_bit_cast(int, (half2v)__builtin_amdgcn_cvt_pkrtz(e11[0], e11[1]));
            const int d3 = __builtin_bit_cast(int, (half2v)__builtin_amdgcn_cvt_pkrtz(e11[2], e11[3]));
            const int q0 = __builtin_amdgcn_ds_bpermute(addrLo, d0);
            const int q1 = __builtin_amdgcn_ds_bpermute(addrLo, d1);
            const int q2 = __builtin_amdgcn_ds_bpermute(addrHi, d0);
            const int q3 = __builtin_amdgcn_ds_bpermute(addrHi, d1);
            const int q4 = __builtin_amdgcn_ds_bpermute(addrLo, d2);
            const int q5 = __builtin_amdgcn_ds_bpermute(addrLo, d3);
            const int q6 = __builtin_amdgcn_ds_bpermute(addrHi, d2);
            const int q7 = __builtin_amdgcn_ds_bpermute(addrHi, d3);
            int4v ai;
            ai[0] = lo32 ? q0 : q4;
            ai[1] = lo32 ? q1 : q5;
            ai[2] = lo32 ? q2 : q6;
            ai[3] = lo32 ? q3 : q7;
            const half8 a2 = __builtin_bit_cast(half8, ai);   // P^T[j=j0+16+l15][i32]
            acc10 = __builtin_amdgcn_mfma_f32_16x16x32_f16(a2, xb0, acc10, 0, 0, 0);
            acc11 = __builtin_amdgcn_mfma_f32_16x16x32_f16(a2, xb1, acc11, 0, 0, 0);
        }

        a0 = na0; a1 = na1; xb0 = nxb0; xb1 = nxb1;
#pragma unroll
        for (int r = 0; r < 4; ++r) {
            c20[r] = -(__builtin_amdgcn_logf(nzz0[r]) + SHIFT * L2E);
            c21[r] = -(__builtin_amdgcn_logf(nzz1[r]) + SHIFT * L2E);
        }
    }

    // block reduction across the 8 waves
#pragma unroll
    for (int r = 0; r < 4; ++r) {
        red[wave][quad * 4 + r][l15]           = acc00[r];
        red[wave][quad * 4 + r][l15 + 16]      = acc01[r];
        red[wave][16 + quad * 4 + r][l15]      = acc10[r];
        red[wave][16 + quad * 4 + r][l15 + 16] = acc11[r];
    }
    __syncthreads();
    {
        const int jj = tid >> 5, c = tid & 31;   // 512 threads: 16 j x 32 c, twice
        const float g = gamma[0];
#pragma unroll
        for (int h = 0; h < 2; ++h) {
            const int j = jj + h * 16;
            float s = 0.f;
#pragma unroll
            for (int w = 0; w < 8; ++w) s += red[w][j][c];
            const size_t o = (size_t)(b * NN + j0 + j) * CC + c;
            out[o] = fmaf(g, s, x[o]);
        }
    }
}

extern "C" void kernel_launch(void* const* d_in, const int* in_sizes, int n_in,
                              void* d_out, int out_size, void* d_ws, size_t ws_size,
                              hipStream_t stream) {
    const float* x     = (const float*)d_in[0];
    const float* gamma = (const float*)d_in[1];
    float* out = (float*)d_out;

    // ws layout: Xf16 (512 KB) | XT f16 (512 KB) | Z fp32 (32 KB)
    _Float16* xf = (_Float16*)d_ws;
    _Float16* xt = xf + (size_t)2 * NN * CC;
    float*    zbuf = (float*)(xt + (size_t)2 * CC * NN);

    k_convert<<<dim3(256), dim3(256), 0, stream>>>(x, xf, xt, zbuf);
    k_pass1 <<<dim3(256), dim3(512), 0, stream>>>(xf, zbuf);
    k_pass2 <<<dim3(256), dim3(512), 0, stream>>>(xf, xt, zbuf, x, gamma, out);
}

// Round 7
// 77.790 us; speedup vs baseline: 1.1248x; 1.0874x over previous
//
#include <hip/hip_runtime.h>

// ChannelAttention b=2, n=4096, c=32 fp32.
// S = X X^T (Gram), softmax over j per row i, out[j,c] = sum_i attn[i,j] x[i,c]; out*g + x.
//
// R9 -> R10: R7/R8/R9 all regressed vs R6 (79.6us) -> R6's structure is a sharp
// local optimum (256 blocks x 512 thr, 1D k1, 32-j k2). R8 bundled a possibly-
// good idea (block-transposed XT) with two bad ones (half grid, fat tiles).
// SINGLE-VARIABLE test this round: exactly R6 + XT2[b][n/32][c][32] layout.
// Mechanism: R6's k2 xt loads walk 16 streams at 8KB stride (one L2 channel
// hotspot); XT2 makes each wave's xt read one contiguous 1KB burst -> should
// recover part of the 14-vs-34.5 TB/s effective-L2-BW gap.
//
// MFMA plan (16x16x32 f16, K = c = 32):
//  k0: convert x -> Xf16 [b][n][c] and XT2 f16 [b][n/32][c][32]  (ws)
//  k1: Z_i = sum_j exp(s_ij - 48); store c2[i] = -log2(Z_i) - 48*log2e
//  k2: per 32-j tile: S-MFMA -> attn=exp2(s*log2e + c2[i]) (fp16)
//      -> in-register quad shuffle (8x ds_bpermute + 4x cndmask per 16-j) -> PV-MFMA.

typedef _Float16 half8 __attribute__((ext_vector_type(8)));
typedef _Float16 half4v __attribute__((ext_vector_type(4)));
typedef _Float16 half2v __attribute__((ext_vector_type(2)));
typedef float float4v __attribute__((ext_vector_type(4)));
typedef int int4v __attribute__((ext_vector_type(4)));

#define NN 4096
#define CC 32
#define L2E 1.44269504f
#define SHIFT 48.0f

// ---------------- k0: fp32 -> fp16 row-major + fp16 block-transposed ----------------
__global__ __launch_bounds__(256) void k_convert(const float* __restrict__ x,
                                                 _Float16* __restrict__ xf,
                                                 _Float16* __restrict__ xt) {
    const int t = blockIdx.x * 256 + threadIdx.x;   // 65536 threads
    const int n  = t & 4095;
    const int cg = (t >> 12) & 7;
    const int b  = t >> 15;
    const int row = (b << 12) | n;
    const float4* src = (const float4*)(x + (size_t)row * CC + cg * 4);
    float4 v = *src;
    _Float16 h0 = (_Float16)v.x, h1 = (_Float16)v.y, h2 = (_Float16)v.z, h3 = (_Float16)v.w;
    *(half4v*)(xf + (size_t)row * CC + cg * 4) = (half4v){h0, h1, h2, h3};
    // XT2[b][n>>5][c][n&31]; consecutive lanes (consecutive n) -> consecutive addrs
    _Float16* p = xt + (size_t)b * CC * NN + (size_t)(n >> 5) * (CC * 32) + cg * 4 * 32 + (n & 31);
    p[0]  = h0;
    p[32] = h1;
    p[64] = h2;
    p[96] = h3;
}

// ---------------- k1: per-row shifted sum-of-exp -> c2[i] ----------------
// Block = 512 threads (8 waves), one 32-row i-tile (2 A-frags); each wave covers
// 512 j's, 4 B-tiles/iter, 1-deep prefetch. 256 blocks total.  [EXACTLY R6]
__global__ __launch_bounds__(512, 2) void k_pass1(const _Float16* __restrict__ xf,
                                                  float* __restrict__ c2out) {
    const int tid = threadIdx.x;
    const int wave = tid >> 6, lane = tid & 63;
    const int quad = lane >> 4, l15 = lane & 15;
    const int b = blockIdx.x >> 7;
    const int i0 = (blockIdx.x & 127) * 32;
    const _Float16* xb = xf + (size_t)b * NN * CC;

    const half8 af0 = *(const half8*)(xb + (size_t)(i0 + l15) * CC + quad * 8);
    const half8 af1 = *(const half8*)(xb + (size_t)(i0 + 16 + l15) * CC + quad * 8);
    const float4v zf = {0.f, 0.f, 0.f, 0.f};
    float z0[4] = {0.f, 0.f, 0.f, 0.f};
    float z1[4] = {0.f, 0.f, 0.f, 0.f};
    const float c2c = -SHIFT * L2E;

    const int jbase = wave * 512;
    half8 b0 = *(const half8*)(xb + (size_t)(jbase + l15) * CC + quad * 8);
    half8 b1 = *(const half8*)(xb + (size_t)(jbase + 16 + l15) * CC + quad * 8);
    half8 b2 = *(const half8*)(xb + (size_t)(jbase + 32 + l15) * CC + quad * 8);
    half8 b3 = *(const half8*)(xb + (size_t)(jbase + 48 + l15) * CC + quad * 8);

    for (int jt = 0; jt < 8; ++jt) {           // 8 iters x 4 tiles x 16 j = 512 j
        const int jn = jbase + ((jt + 1) & 7) * 64;   // wraps on last iter (harmless)
        half8 n0 = *(const half8*)(xb + (size_t)(jn + l15) * CC + quad * 8);
        half8 n1 = *(const half8*)(xb + (size_t)(jn + 16 + l15) * CC + quad * 8);
        half8 n2 = *(const half8*)(xb + (size_t)(jn + 32 + l15) * CC + quad * 8);
        half8 n3 = *(const half8*)(xb + (size_t)(jn + 48 + l15) * CC + quad * 8);

        float4v s00 = __builtin_amdgcn_mfma_f32_16x16x32_f16(af0, b0, zf, 0, 0, 0);
        float4v s01 = __builtin_amdgcn_mfma_f32_16x16x32_f16(af0, b1, zf, 0, 0, 0);
        float4v s02 = __builtin_amdgcn_mfma_f32_16x16x32_f16(af0, b2, zf, 0, 0, 0);
        float4v s03 = __builtin_amdgcn_mfma_f32_16x16x32_f16(af0, b3, zf, 0, 0, 0);
        float4v s10 = __builtin_amdgcn_mfma_f32_16x16x32_f16(af1, b0, zf, 0, 0, 0);
        float4v s11 = __builtin_amdgcn_mfma_f32_16x16x32_f16(af1, b1, zf, 0, 0, 0);
        float4v s12 = __builtin_amdgcn_mfma_f32_16x16x32_f16(af1, b2, zf, 0, 0, 0);
        float4v s13 = __builtin_amdgcn_mfma_f32_16x16x32_f16(af1, b3, zf, 0, 0, 0);
#pragma unroll
        for (int r = 0; r < 4; ++r) {
            z0[r] += __builtin_amdgcn_exp2f(fmaf(s00[r], L2E, c2c));
            z0[r] += __builtin_amdgcn_exp2f(fmaf(s01[r], L2E, c2c));
            z0[r] += __builtin_amdgcn_exp2f(fmaf(s02[r], L2E, c2c));
            z0[r] += __builtin_amdgcn_exp2f(fmaf(s03[r], L2E, c2c));
            z1[r] += __builtin_amdgcn_exp2f(fmaf(s10[r], L2E, c2c));
            z1[r] += __builtin_amdgcn_exp2f(fmaf(s11[r], L2E, c2c));
            z1[r] += __builtin_amdgcn_exp2f(fmaf(s12[r], L2E, c2c));
            z1[r] += __builtin_amdgcn_exp2f(fmaf(s13[r], L2E, c2c));
        }
        b0 = n0; b1 = n1; b2 = n2; b3 = n3;
    }
    // combine over the 16 j-lanes within each quad group
#pragma unroll
    for (int off = 1; off <= 8; off <<= 1) {
#pragma unroll
        for (int r = 0; r < 4; ++r) {
            z0[r] += __shfl_xor(z0[r], off, 64);
            z1[r] += __shfl_xor(z1[r], off, 64);
        }
    }
    __shared__ float zw[8][32];
    if (l15 == 0) {
#pragma unroll
        for (int r = 0; r < 4; ++r) {
            zw[wave][quad * 4 + r]      = z0[r];
            zw[wave][16 + quad * 4 + r] = z1[r];
        }
    }
    __syncthreads();
    if (tid < 32) {
        float zs = 0.f;
#pragma unroll
        for (int w = 0; w < 8; ++w) zs += zw[w][tid];
        c2out[b * NN + i0 + tid] = -(__builtin_amdgcn_logf(zs) + SHIFT * L2E);
    }
}

// ---------------- k2: output pass ----------------
// Block = 512 threads (8 waves), one 32-j tile (2 B-frags); wave w covers i in
// [w*512,(w+1)*512), 32 i per iteration (16 iters). 256 blocks total.
// xt reads use XT2 layout: one contiguous 1KB burst per wave per i32-block.
// C->A transpose in registers per 16-j subtile: 8x ds_bpermute + 4x cndmask.
__global__ __launch_bounds__(512, 2) void k_pass2(const _Float16* __restrict__ xf,
                                                  const _Float16* __restrict__ xt,
                                                  const float* __restrict__ c2,
                                                  const float* __restrict__ x,
                                                  const float* __restrict__ gamma,
                                                  float* __restrict__ out) {
    const int tid = threadIdx.x;
    const int wave = tid >> 6, lane = tid & 63;
    const int quad = lane >> 4, l15 = lane & 15;
    const int b = blockIdx.x >> 7;
    const int j0 = (blockIdx.x & 127) * 32;
    const _Float16* xb  = xf + (size_t)b * NN * CC;
    const _Float16* xtb = xt + (size_t)b * CC * NN;   // XT2 [n/32][c][32]
    const float* c2b = c2 + b * NN;

    __shared__ float red[8][32][32];

    // bpermute byte addresses: A0/A1 pull from lane ((q&1)*32 + j15),
    // A2/A3 from lane ((q&1)*32 + 16 + j15). Select p0 (q<2) vs p1 (q>=2) data.
    const int addrLo = (((quad & 1) << 5) + l15) << 2;
    const int addrHi = addrLo + 64;
    const bool lo32 = (lane < 32);

    const half8 bj0 = *(const half8*)(xb + (size_t)(j0 + l15) * CC + quad * 8);
    const half8 bj1 = *(const half8*)(xb + (size_t)(j0 + 16 + l15) * CC + quad * 8);
    const float4v zf = {0.f, 0.f, 0.f, 0.f};
    float4v acc00 = zf, acc01 = zf, acc10 = zf, acc11 = zf;

    const int ibase = wave * 512;
    half8 a0  = *(const half8*)(xb + (size_t)(ibase + l15) * CC + quad * 8);
    half8 a1  = *(const half8*)(xb + (size_t)(ibase + 16 + l15) * CC + quad * 8);
    // XT2: i32-block at ibase -> contiguous [c][32]; c=l15 (xb0) / l15+16 (xb1)
    half8 xb0 = *(const half8*)(xtb + (size_t)ibase * 32 + l15 * 32 + quad * 8);
    half8 xb1 = *(const half8*)(xtb + (size_t)ibase * 32 + (l15 + 16) * 32 + quad * 8);
    float4v c20 = *(const float4v*)(c2b + ibase + quad * 4);
    float4v c21 = *(const float4v*)(c2b + ibase + 16 + quad * 4);

    for (int it = 0; it < 16; ++it) {
        const int inx = ibase + ((it + 1) & 15) * 32;   // wraps on last iter
        half8 na0  = *(const half8*)(xb + (size_t)(inx + l15) * CC + quad * 8);
        half8 na1  = *(const half8*)(xb + (size_t)(inx + 16 + l15) * CC + quad * 8);
        half8 nxb0 = *(const half8*)(xtb + (size_t)inx * 32 + l15 * 32 + quad * 8);
        half8 nxb1 = *(const half8*)(xtb + (size_t)inx * 32 + (l15 + 16) * 32 + quad * 8);
        float4v nc20 = *(const float4v*)(c2b + inx + quad * 4);
        float4v nc21 = *(const float4v*)(c2b + inx + 16 + quad * 4);

        float4v s00 = __builtin_amdgcn_mfma_f32_16x16x32_f16(a0, bj0, zf, 0, 0, 0);
        float4v s10 = __builtin_amdgcn_mfma_f32_16x16x32_f16(a1, bj0, zf, 0, 0, 0);
        float4v s01 = __builtin_amdgcn_mfma_f32_16x16x32_f16(a0, bj1, zf, 0, 0, 0);
        float4v s11 = __builtin_amdgcn_mfma_f32_16x16x32_f16(a1, bj1, zf, 0, 0, 0);
        float4v e00, e10, e01, e11;
#pragma unroll
        for (int r = 0; r < 4; ++r) {
            e00[r] = __builtin_amdgcn_exp2f(fmaf(s00[r], L2E, c20[r]));
            e10[r] = __builtin_amdgcn_exp2f(fmaf(s10[r], L2E, c21[r]));
            e01[r] = __builtin_amdgcn_exp2f(fmaf(s01[r], L2E, c20[r]));
            e11[r] = __builtin_amdgcn_exp2f(fmaf(s11[r], L2E, c21[r]));
        }
        // ---- subtile 0 (j = j0..j0+15) transpose ----
        {
            const int d0 = __builtin_bit_cast(int, (half2v)__builtin_amdgcn_cvt_pkrtz(e00[0], e00[1]));
            const int d1 = __builtin_bit_cast(int, (half2v)__builtin_amdgcn_cvt_pkrtz(e00[2], e00[3]));
            const int d2 = __builtin_bit_cast(int, (half2v)__builtin_amdgcn_cvt_pkrtz(e10[0], e10[1]));
            const int d3 = __builtin_bit_cast(int, (half2v)__builtin_amdgcn_cvt_pkrtz(e10[2], e10[3]));
            const int q0 = __builtin_amdgcn_ds_bpermute(addrLo, d0);
            const int q1 = __builtin_amdgcn_ds_bpermute(addrLo, d1);
            const int q2 = __builtin_amdgcn_ds_bpermute(addrHi, d0);
            const int q3 = __builtin_amdgcn_ds_bpermute(addrHi, d1);
            const int q4 = __builtin_amdgcn_ds_bpermute(addrLo, d2);
            const int q5 = __builtin_amdgcn_ds_bpermute(addrLo, d3);
            const int q6 = __builtin_amdgcn_ds_bpermute(addrHi, d2);
            const int q7 = __builtin_amdgcn_ds_bpermute(addrHi, d3);
            int4v ai;
            ai[0] = lo32 ? q0 : q4;
            ai[1] = lo32 ? q1 : q5;
            ai[2] = lo32 ? q2 : q6;
            ai[3] = lo32 ? q3 : q7;
            const half8 a2 = __builtin_bit_cast(half8, ai);   // P^T[j=j0+l15][i32]
            acc00 = __builtin_amdgcn_mfma_f32_16x16x32_f16(a2, xb0, acc00, 0, 0, 0);
            acc01 = __builtin_amdgcn_mfma_f32_16x16x32_f16(a2, xb1, acc01, 0, 0, 0);
        }
        // ---- subtile 1 (j = j0+16..j0+31) transpose ----
        {
            const int d0 = __builtin_bit_cast(int, (half2v)__builtin_amdgcn_cvt_pkrtz(e01[0], e01[1]));
            const int d1 = __builtin_bit_cast(int, (half2v)__builtin_amdgcn_cvt_pkrtz(e01[2], e01[3]));
            const int d2 = __builtin_bit_cast(int, (half2v)__builtin_amdgcn_cvt_pkrtz(e11[0], e11[1]));
            const int d3 = __builtin_bit_cast(int, (half2v)__builtin_amdgcn_cvt_pkrtz(e11[2], e11[3]));
            const int q0 = __builtin_amdgcn_ds_bpermute(addrLo, d0);
            const int q1 = __builtin_amdgcn_ds_bpermute(addrLo, d1);
            const int q2 = __builtin_amdgcn_ds_bpermute(addrHi, d0);
            const int q3 = __builtin_amdgcn_ds_bpermute(addrHi, d1);
            const int q4 = __builtin_amdgcn_ds_bpermute(addrLo, d2);
            const int q5 = __builtin_amdgcn_ds_bpermute(addrLo, d3);
            const int q6 = __builtin_amdgcn_ds_bpermute(addrHi, d2);
            const int q7 = __builtin_amdgcn_ds_bpermute(addrHi, d3);
            int4v ai;
            ai[0] = lo32 ? q0 : q4;
            ai[1] = lo32 ? q1 : q5;
            ai[2] = lo32 ? q2 : q6;
            ai[3] = lo32 ? q3 : q7;
            const half8 a2 = __builtin_bit_cast(half8, ai);   // P^T[j=j0+16+l15][i32]
            acc10 = __builtin_amdgcn_mfma_f32_16x16x32_f16(a2, xb0, acc10, 0, 0, 0);
            acc11 = __builtin_amdgcn_mfma_f32_16x16x32_f16(a2, xb1, acc11, 0, 0, 0);
        }

        a0 = na0; a1 = na1; xb0 = nxb0; xb1 = nxb1; c20 = nc20; c21 = nc21;
    }

    // block reduction across the 8 waves
#pragma unroll
    for (int r = 0; r < 4; ++r) {
        red[wave][quad * 4 + r][l15]           = acc00[r];
        red[wave][quad * 4 + r][l15 + 16]      = acc01[r];
        red[wave][16 + quad * 4 + r][l15]      = acc10[r];
        red[wave][16 + quad * 4 + r][l15 + 16] = acc11[r];
    }
    __syncthreads();
    {
        const int jj = tid >> 5, c = tid & 31;   // 512 threads: 16 j x 32 c, twice
        const float g = gamma[0];
#pragma unroll
        for (int h = 0; h < 2; ++h) {
            const int j = jj + h * 16;
            float s = 0.f;
#pragma unroll
            for (int w = 0; w < 8; ++w) s += red[w][j][c];
            const size_t o = (size_t)(b * NN + j0 + j) * CC + c;
            out[o] = fmaf(g, s, x[o]);
        }
    }
}

extern "C" void kernel_launch(void* const* d_in, const int* in_sizes, int n_in,
                              void* d_out, int out_size, void* d_ws, size_t ws_size,
                              hipStream_t stream) {
    const float* x     = (const float*)d_in[0];
    const float* gamma = (const float*)d_in[1];
    float* out = (float*)d_out;

    // ws layout: Xf16 (512 KB) | XT2 f16 (512 KB) | c2 fp32 (32 KB)
    _Float16* xf = (_Float16*)d_ws;
    _Float16* xt = xf + (size_t)2 * NN * CC;
    float*    c2 = (float*)(xt + (size_t)2 * CC * NN);

    k_convert<<<dim3(256), dim3(256), 0, stream>>>(x, xf, xt);
    k_pass1 <<<dim3(256), dim3(512), 0, stream>>>(xf, c2);
    k_pass2 <<<dim3(256), dim3(512), 0, stream>>>(xf, xt, c2, x, gamma, out);
}

// Round 8
// 76.568 us; speedup vs baseline: 1.1427x; 1.0160x over previous
//
#include <hip/hip_runtime.h>

// ChannelAttention b=2, n=4096, c=32 fp32.
// S = X X^T (Gram), softmax over j per row i, out[j,c] = sum_i attn[i,j] x[i,c]; out*g + x.
//
// R10 -> R11: R10 (XT2 layout) = best, 77.8us. This round tests "R8's traffic
// cut at R6's full-chip grid": k2 becomes 256 blocks = 2b x 64 j-tiles(64j) x
// 2 i-halves(2048i). Per block 256KB -> k2 L2 traffic 128->66 MB with ALL 256
// CUs busy (R8's same cut at 128 blocks idled half the chip and lost).
// Outputs now have 2 contributors -> k0 zeroes d_out, k2 ends with one
// atomicAdd per output element (ih=0 block also adds the +x residual).
// k1 / inner-loop math exactly R10 (c2 precomputed; no in-loop logs - R9's
// mistake). Prediction: -4.4us BW minus ~1.5us atomic overhead -> ~74-76us.
//
// MFMA plan (16x16x32 f16, K = c = 32):
//  k0: convert x -> Xf16 [b][n][c] and XT2 f16 [b][n/32][c][32]; zero out
//  k1: Z_i = sum_j exp(s_ij - 48); store c2[i] = -log2(Z_i) - 48*log2e
//  k2: per (64-j, i-half) tile: S-MFMA -> attn=exp2(s*log2e + c2[i]) (fp16)
//      -> in-register quad shuffle -> PV-MFMA -> LDS 8-wave reduce -> atomicAdd.

typedef _Float16 half8 __attribute__((ext_vector_type(8)));
typedef _Float16 half4v __attribute__((ext_vector_type(4)));
typedef _Float16 half2v __attribute__((ext_vector_type(2)));
typedef float float4v __attribute__((ext_vector_type(4)));
typedef int int4v __attribute__((ext_vector_type(4)));

#define NN 4096
#define CC 32
#define L2E 1.44269504f
#define SHIFT 48.0f

// ---------------- k0: fp32 -> fp16 row-major + fp16 block-transposed + zero out ----------------
__global__ __launch_bounds__(256) void k_convert(const float* __restrict__ x,
                                                 _Float16* __restrict__ xf,
                                                 _Float16* __restrict__ xt,
                                                 float* __restrict__ out) {
    const int t = blockIdx.x * 256 + threadIdx.x;   // 65536 threads
    const int n  = t & 4095;
    const int cg = (t >> 12) & 7;
    const int b  = t >> 15;
    const int row = (b << 12) | n;
    const float4* src = (const float4*)(x + (size_t)row * CC + cg * 4);
    float4 v = *src;
    _Float16 h0 = (_Float16)v.x, h1 = (_Float16)v.y, h2 = (_Float16)v.z, h3 = (_Float16)v.w;
    *(half4v*)(xf + (size_t)row * CC + cg * 4) = (half4v){h0, h1, h2, h3};
    // XT2[b][n>>5][c][n&31]; consecutive lanes (consecutive n) -> consecutive addrs
    _Float16* p = xt + (size_t)b * CC * NN + (size_t)(n >> 5) * (CC * 32) + cg * 4 * 32 + (n & 31);
    p[0]  = h0;
    p[32] = h1;
    p[64] = h2;
    p[96] = h3;
    // zero d_out for k2's atomicAdd epilogue (262144 floats / 65536 threads = 4)
    *(float4*)(out + (size_t)t * 4) = (float4){0.f, 0.f, 0.f, 0.f};
}

// ---------------- k1: per-row shifted sum-of-exp -> c2[i] ----------------
// Block = 512 threads (8 waves), one 32-row i-tile (2 A-frags); each wave covers
// 512 j's, 4 B-tiles/iter, 1-deep prefetch. 256 blocks total.  [EXACTLY R10]
__global__ __launch_bounds__(512, 2) void k_pass1(const _Float16* __restrict__ xf,
                                                  float* __restrict__ c2out) {
    const int tid = threadIdx.x;
    const int wave = tid >> 6, lane = tid & 63;
    const int quad = lane >> 4, l15 = lane & 15;
    const int b = blockIdx.x >> 7;
    const int i0 = (blockIdx.x & 127) * 32;
    const _Float16* xb = xf + (size_t)b * NN * CC;

    const half8 af0 = *(const half8*)(xb + (size_t)(i0 + l15) * CC + quad * 8);
    const half8 af1 = *(const half8*)(xb + (size_t)(i0 + 16 + l15) * CC + quad * 8);
    const float4v zf = {0.f, 0.f, 0.f, 0.f};
    float z0[4] = {0.f, 0.f, 0.f, 0.f};
    float z1[4] = {0.f, 0.f, 0.f, 0.f};
    const float c2c = -SHIFT * L2E;

    const int jbase = wave * 512;
    half8 b0 = *(const half8*)(xb + (size_t)(jbase + l15) * CC + quad * 8);
    half8 b1 = *(const half8*)(xb + (size_t)(jbase + 16 + l15) * CC + quad * 8);
    half8 b2 = *(const half8*)(xb + (size_t)(jbase + 32 + l15) * CC + quad * 8);
    half8 b3 = *(const half8*)(xb + (size_t)(jbase + 48 + l15) * CC + quad * 8);

    for (int jt = 0; jt < 8; ++jt) {           // 8 iters x 4 tiles x 16 j = 512 j
        const int jn = jbase + ((jt + 1) & 7) * 64;   // wraps on last iter (harmless)
        half8 n0 = *(const half8*)(xb + (size_t)(jn + l15) * CC + quad * 8);
        half8 n1 = *(const half8*)(xb + (size_t)(jn + 16 + l15) * CC + quad * 8);
        half8 n2 = *(const half8*)(xb + (size_t)(jn + 32 + l15) * CC + quad * 8);
        half8 n3 = *(const half8*)(xb + (size_t)(jn + 48 + l15) * CC + quad * 8);

        float4v s00 = __builtin_amdgcn_mfma_f32_16x16x32_f16(af0, b0, zf, 0, 0, 0);
        float4v s01 = __builtin_amdgcn_mfma_f32_16x16x32_f16(af0, b1, zf, 0, 0, 0);
        float4v s02 = __builtin_amdgcn_mfma_f32_16x16x32_f16(af0, b2, zf, 0, 0, 0);
        float4v s03 = __builtin_amdgcn_mfma_f32_16x16x32_f16(af0, b3, zf, 0, 0, 0);
        float4v s10 = __builtin_amdgcn_mfma_f32_16x16x32_f16(af1, b0, zf, 0, 0, 0);
        float4v s11 = __builtin_amdgcn_mfma_f32_16x16x32_f16(af1, b1, zf, 0, 0, 0);
        float4v s12 = __builtin_amdgcn_mfma_f32_16x16x32_f16(af1, b2, zf, 0, 0, 0);
        float4v s13 = __builtin_amdgcn_mfma_f32_16x16x32_f16(af1, b3, zf, 0, 0, 0);
#pragma unroll
        for (int r = 0; r < 4; ++r) {
            z0[r] += __builtin_amdgcn_exp2f(fmaf(s00[r], L2E, c2c));
            z0[r] += __builtin_amdgcn_exp2f(fmaf(s01[r], L2E, c2c));
            z0[r] += __builtin_amdgcn_exp2f(fmaf(s02[r], L2E, c2c));
            z0[r] += __builtin_amdgcn_exp2f(fmaf(s03[r], L2E, c2c));
            z1[r] += __builtin_amdgcn_exp2f(fmaf(s10[r], L2E, c2c));
            z1[r] += __builtin_amdgcn_exp2f(fmaf(s11[r], L2E, c2c));
            z1[r] += __builtin_amdgcn_exp2f(fmaf(s12[r], L2E, c2c));
            z1[r] += __builtin_amdgcn_exp2f(fmaf(s13[r], L2E, c2c));
        }
        b0 = n0; b1 = n1; b2 = n2; b3 = n3;
    }
    // combine over the 16 j-lanes within each quad group
#pragma unroll
    for (int off = 1; off <= 8; off <<= 1) {
#pragma unroll
        for (int r = 0; r < 4; ++r) {
            z0[r] += __shfl_xor(z0[r], off, 64);
            z1[r] += __shfl_xor(z1[r], off, 64);
        }
    }
    __shared__ float zw[8][32];
    if (l15 == 0) {
#pragma unroll
        for (int r = 0; r < 4; ++r) {
            zw[wave][quad * 4 + r]      = z0[r];
            zw[wave][16 + quad * 4 + r] = z1[r];
        }
    }
    __syncthreads();
    if (tid < 32) {
        float zs = 0.f;
#pragma unroll
        for (int w = 0; w < 8; ++w) zs += zw[w][tid];
        c2out[b * NN + i0 + tid] = -(__builtin_amdgcn_logf(zs) + SHIFT * L2E);
    }
}

// ---------------- k2: output pass (64-j tile x i-half, atomicAdd merge) ----------------
// 256 blocks: bit layout blockIdx = b(1) | jt(6) | ih(1). Block covers j0=jt*64
// (4 B-frags) and i in [ih*2048, ih*2048+2048): wave w covers 256 i = 8 iters x 32 i.
// Two phases per iter (j-subtiles 0,1 then 2,3). Epilogue: 8-wave LDS reduce,
// then atomicAdd into zeroed out (ih=0 also adds the +x residual).
__global__ __launch_bounds__(512, 2) void k_pass2(const _Float16* __restrict__ xf,
                                                  const _Float16* __restrict__ xt,
                                                  const float* __restrict__ c2,
                                                  const float* __restrict__ x,
                                                  const float* __restrict__ gamma,
                                                  float* __restrict__ out) {
    const int tid = threadIdx.x;
    const int wave = tid >> 6, lane = tid & 63;
    const int quad = lane >> 4, l15 = lane & 15;
    const int ih = blockIdx.x & 1;
    const int j0 = ((blockIdx.x >> 1) & 63) * 64;
    const int b  = blockIdx.x >> 7;
    const _Float16* xb  = xf + (size_t)b * NN * CC;
    const _Float16* xtb = xt + (size_t)b * CC * NN;   // XT2 [n/32][c][32]
    const float* c2b = c2 + b * NN;

    __shared__ float red[8][64][32];   // 64 KB

    const int addrLo = (((quad & 1) << 5) + l15) << 2;
    const int addrHi = addrLo + 64;
    const bool lo32 = (lane < 32);

    const half8 bj0 = *(const half8*)(xb + (size_t)(j0 + l15) * CC + quad * 8);
    const half8 bj1 = *(const half8*)(xb + (size_t)(j0 + 16 + l15) * CC + quad * 8);
    const half8 bj2 = *(const half8*)(xb + (size_t)(j0 + 32 + l15) * CC + quad * 8);
    const half8 bj3 = *(const half8*)(xb + (size_t)(j0 + 48 + l15) * CC + quad * 8);
    const float4v zf = {0.f, 0.f, 0.f, 0.f};
    float4v acc00 = zf, acc01 = zf, acc10 = zf, acc11 = zf;
    float4v acc20 = zf, acc21 = zf, acc30 = zf, acc31 = zf;

    const int ibase = ih * 2048 + wave * 256;
    half8 a0  = *(const half8*)(xb + (size_t)(ibase + l15) * CC + quad * 8);
    half8 a1  = *(const half8*)(xb + (size_t)(ibase + 16 + l15) * CC + quad * 8);
    half8 xb0 = *(const half8*)(xtb + (size_t)ibase * 32 + l15 * 32 + quad * 8);
    half8 xb1 = *(const half8*)(xtb + (size_t)ibase * 32 + (l15 + 16) * 32 + quad * 8);
    float4v c20 = *(const float4v*)(c2b + ibase + quad * 4);
    float4v c21 = *(const float4v*)(c2b + ibase + 16 + quad * 4);

    for (int it = 0; it < 8; ++it) {
        const int inx = ibase + ((it + 1) & 7) * 32;   // wraps on last iter
        half8 na0  = *(const half8*)(xb + (size_t)(inx + l15) * CC + quad * 8);
        half8 na1  = *(const half8*)(xb + (size_t)(inx + 16 + l15) * CC + quad * 8);
        half8 nxb0 = *(const half8*)(xtb + (size_t)inx * 32 + l15 * 32 + quad * 8);
        half8 nxb1 = *(const half8*)(xtb + (size_t)inx * 32 + (l15 + 16) * 32 + quad * 8);
        float4v nc20 = *(const float4v*)(c2b + inx + quad * 4);
        float4v nc21 = *(const float4v*)(c2b + inx + 16 + quad * 4);

        // ---- phase A: j-subtiles 0,1 ----
        {
            float4v s00 = __builtin_amdgcn_mfma_f32_16x16x32_f16(a0, bj0, zf, 0, 0, 0);
            float4v s10 = __builtin_amdgcn_mfma_f32_16x16x32_f16(a1, bj0, zf, 0, 0, 0);
            float4v s01 = __builtin_amdgcn_mfma_f32_16x16x32_f16(a0, bj1, zf, 0, 0, 0);
            float4v s11 = __builtin_amdgcn_mfma_f32_16x16x32_f16(a1, bj1, zf, 0, 0, 0);
            float4v e00, e10, e01, e11;
#pragma unroll
            for (int r = 0; r < 4; ++r) {
                e00[r] = __builtin_amdgcn_exp2f(fmaf(s00[r], L2E, c20[r]));
                e10[r] = __builtin_amdgcn_exp2f(fmaf(s10[r], L2E, c21[r]));
                e01[r] = __builtin_amdgcn_exp2f(fmaf(s01[r], L2E, c20[r]));
                e11[r] = __builtin_amdgcn_exp2f(fmaf(s11[r], L2E, c21[r]));
            }
            {
                const int d0 = __builtin_bit_cast(int, (half2v)__builtin_amdgcn_cvt_pkrtz(e00[0], e00[1]));
                const int d1 = __builtin_bit_cast(int, (half2v)__builtin_amdgcn_cvt_pkrtz(e00[2], e00[3]));
                const int d2 = __builtin_bit_cast(int, (half2v)__builtin_amdgcn_cvt_pkrtz(e10[0], e10[1]));
                const int d3 = __builtin_bit_cast(int, (half2v)__builtin_amdgcn_cvt_pkrtz(e10[2], e10[3]));
                const int q0 = __builtin_amdgcn_ds_bpermute(addrLo, d0);
                const int q1 = __builtin_amdgcn_ds_bpermute(addrLo, d1);
                const int q2 = __builtin_amdgcn_ds_bpermute(addrHi, d0);
                const int q3 = __builtin_amdgcn_ds_bpermute(addrHi, d1);
                const int q4 = __builtin_amdgcn_ds_bpermute(addrLo, d2);
                const int q5 = __builtin_amdgcn_ds_bpermute(addrLo, d3);
                const int q6 = __builtin_amdgcn_ds_bpermute(addrHi, d2);
                const int q7 = __builtin_amdgcn_ds_bpermute(addrHi, d3);
                int4v ai;
                ai[0] = lo32 ? q0 : q4;
                ai[1] = lo32 ? q1 : q5;
                ai[2] = lo32 ? q2 : q6;
                ai[3] = lo32 ? q3 : q7;
                const half8 a2 = __builtin_bit_cast(half8, ai);   // P^T[j=j0+l15][i32]
                acc00 = __builtin_amdgcn_mfma_f32_16x16x32_f16(a2, xb0, acc00, 0, 0, 0);
                acc01 = __builtin_amdgcn_mfma_f32_16x16x32_f16(a2, xb1, acc01, 0, 0, 0);
            }
            {
                const int d0 = __builtin_bit_cast(int, (half2v)__builtin_amdgcn_cvt_pkrtz(e01[0], e01[1]));
                const int d1 = __builtin_bit_cast(int, (half2v)__builtin_amdgcn_cvt_pkrtz(e01[2], e01[3]));
                const int d2 = __builtin_bit_cast(int, (half2v)__builtin_amdgcn_cvt_pkrtz(e11[0], e11[1]));
                const int d3 = __builtin_bit_cast(int, (half2v)__builtin_amdgcn_cvt_pkrtz(e11[2], e11[3]));
                const int q0 = __builtin_amdgcn_ds_bpermute(addrLo, d0);
                const int q1 = __builtin_amdgcn_ds_bpermute(addrLo, d1);
                const int q2 = __builtin_amdgcn_ds_bpermute(addrHi, d0);
                const int q3 = __builtin_amdgcn_ds_bpermute(addrHi, d1);
                const int q4 = __builtin_amdgcn_ds_bpermute(addrLo, d2);
                const int q5 = __builtin_amdgcn_ds_bpermute(addrLo, d3);
                const int q6 = __builtin_amdgcn_ds_bpermute(addrHi, d2);
                const int q7 = __builtin_amdgcn_ds_bpermute(addrHi, d3);
                int4v ai;
                ai[0] = lo32 ? q0 : q4;
                ai[1] = lo32 ? q1 : q5;
                ai[2] = lo32 ? q2 : q6;
                ai[3] = lo32 ? q3 : q7;
                const half8 a2 = __builtin_bit_cast(half8, ai);   // P^T[j=j0+16+l15][i32]
                acc10 = __builtin_amdgcn_mfma_f32_16x16x32_f16(a2, xb0, acc10, 0, 0, 0);
                acc11 = __builtin_amdgcn_mfma_f32_16x16x32_f16(a2, xb1, acc11, 0, 0, 0);
            }
        }
        // ---- phase B: j-subtiles 2,3 ----
        {
            float4v s00 = __builtin_amdgcn_mfma_f32_16x16x32_f16(a0, bj2, zf, 0, 0, 0);
            float4v s10 = __builtin_amdgcn_mfma_f32_16x16x32_f16(a1, bj2, zf, 0, 0, 0);
            float4v s01 = __builtin_amdgcn_mfma_f32_16x16x32_f16(a0, bj3, zf, 0, 0, 0);
            float4v s11 = __builtin_amdgcn_mfma_f32_16x16x32_f16(a1, bj3, zf, 0, 0, 0);
            float4v e00, e10, e01, e11;
#pragma unroll
            for (int r = 0; r < 4; ++r) {
                e00[r] = __builtin_amdgcn_exp2f(fmaf(s00[r], L2E, c20[r]));
                e10[r] = __builtin_amdgcn_exp2f(fmaf(s10[r], L2E, c21[r]));
                e01[r] = __builtin_amdgcn_exp2f(fmaf(s01[r], L2E, c20[r]));
                e11[r] = __builtin_amdgcn_exp2f(fmaf(s11[r], L2E, c21[r]));
            }
            {
                const int d0 = __builtin_bit_cast(int, (half2v)__builtin_amdgcn_cvt_pkrtz(e00[0], e00[1]));
                const int d1 = __builtin_bit_cast(int, (half2v)__builtin_amdgcn_cvt_pkrtz(e00[2], e00[3]));
                const int d2 = __builtin_bit_cast(int, (half2v)__builtin_amdgcn_cvt_pkrtz(e10[0], e10[1]));
                const int d3 = __builtin_bit_cast(int, (half2v)__builtin_amdgcn_cvt_pkrtz(e10[2], e10[3]));
                const int q0 = __builtin_amdgcn_ds_bpermute(addrLo, d0);
                const int q1 = __builtin_amdgcn_ds_bpermute(addrLo, d1);
                const int q2 = __builtin_amdgcn_ds_bpermute(addrHi, d0);
                const int q3 = __builtin_amdgcn_ds_bpermute(addrHi, d1);
                const int q4 = __builtin_amdgcn_ds_bpermute(addrLo, d2);
                const int q5 = __builtin_amdgcn_ds_bpermute(addrLo, d3);
                const int q6 = __builtin_amdgcn_ds_bpermute(addrHi, d2);
                const int q7 = __builtin_amdgcn_ds_bpermute(addrHi, d3);
                int4v ai;
                ai[0] = lo32 ? q0 : q4;
                ai[1] = lo32 ? q1 : q5;
                ai[2] = lo32 ? q2 : q6;
                ai[3] = lo32 ? q3 : q7;
                const half8 a2 = __builtin_bit_cast(half8, ai);   // P^T[j=j0+32+l15][i32]
                acc20 = __builtin_amdgcn_mfma_f32_16x16x32_f16(a2, xb0, acc20, 0, 0, 0);
                acc21 = __builtin_amdgcn_mfma_f32_16x16x32_f16(a2, xb1, acc21, 0, 0, 0);
            }
            {
                const int d0 = __builtin_bit_cast(int, (half2v)__builtin_amdgcn_cvt_pkrtz(e01[0], e01[1]));
                const int d1 = __builtin_bit_cast(int, (half2v)__builtin_amdgcn_cvt_pkrtz(e01[2], e01[3]));
                const int d2 = __builtin_bit_cast(int, (half2v)__builtin_amdgcn_cvt_pkrtz(e11[0], e11[1]));
                const int d3 = __builtin_bit_cast(int, (half2v)__builtin_amdgcn_cvt_pkrtz(e11[2], e11[3]));
                const int q0 = __builtin_amdgcn_ds_bpermute(addrLo, d0);
                const int q1 = __builtin_amdgcn_ds_bpermute(addrLo, d1);
                const int q2 = __builtin_amdgcn_ds_bpermute(addrHi, d0);
                const int q3 = __builtin_amdgcn_ds_bpermute(addrHi, d1);
                const int q4 = __builtin_amdgcn_ds_bpermute(addrLo, d2);
                const int q5 = __builtin_amdgcn_ds_bpermute(addrLo, d3);
                const int q6 = __builtin_amdgcn_ds_bpermute(addrHi, d2);
                const int q7 = __builtin_amdgcn_ds_bpermute(addrHi, d3);
                int4v ai;
                ai[0] = lo32 ? q0 : q4;
                ai[1] = lo32 ? q1 : q5;
                ai[2] = lo32 ? q2 : q6;
                ai[3] = lo32 ? q3 : q7;
                const half8 a2 = __builtin_bit_cast(half8, ai);   // P^T[j=j0+48+l15][i32]
                acc30 = __builtin_amdgcn_mfma_f32_16x16x32_f16(a2, xb0, acc30, 0, 0, 0);
                acc31 = __builtin_amdgcn_mfma_f32_16x16x32_f16(a2, xb1, acc31, 0, 0, 0);
            }
        }

        a0 = na0; a1 = na1; xb0 = nxb0; xb1 = nxb1; c20 = nc20; c21 = nc21;
    }

    // 8-wave LDS reduction, then one atomicAdd per output element
#pragma unroll
    for (int r = 0; r < 4; ++r) {
        red[wave][quad * 4 + r][l15]           = acc00[r];
        red[wave][quad * 4 + r][l15 + 16]      = acc01[r];
        red[wave][16 + quad * 4 + r][l15]      = acc10[r];
        red[wave][16 + quad * 4 + r][l15 + 16] = acc11[r];
        red[wave][32 + quad * 4 + r][l15]      = acc20[r];
        red[wave][32 + quad * 4 + r][l15 + 16] = acc21[r];
        red[wave][48 + quad * 4 + r][l15]      = acc30[r];
        red[wave][48 + quad * 4 + r][l15 + 16] = acc31[r];
    }
    __syncthreads();
    {
        const int jj = tid >> 5, c = tid & 31;   // 512 threads: 16 j x 32 c, x4
        const float g = gamma[0];
#pragma unroll
        for (int h = 0; h < 4; ++h) {
            const int j = jj + h * 16;
            float s = 0.f;
#pragma unroll
            for (int w = 0; w < 8; ++w) s += red[w][j][c];
            const size_t o = (size_t)(b * NN + j0 + j) * CC + c;
            float v = g * s;
            if (ih == 0) v += x[o];              // add the residual exactly once
            atomicAdd(&out[o], v);
        }
    }
}

extern "C" void kernel_launch(void* const* d_in, const int* in_sizes, int n_in,
                              void* d_out, int out_size, void* d_ws, size_t ws_size,
                              hipStream_t stream) {
    const float* x     = (const float*)d_in[0];
    const float* gamma = (const float*)d_in[1];
    float* out = (float*)d_out;

    // ws layout: Xf16 (512 KB) | XT2 f16 (512 KB) | c2 fp32 (32 KB)
    _Float16* xf = (_Float16*)d_ws;
    _Float16* xt = xf + (size_t)2 * NN * CC;
    float*    c2 = (float*)(xt + (size_t)2 * CC * NN);

    k_convert<<<dim3(256), dim3(256), 0, stream>>>(x, xf, xt, out);
    k_pass1 <<<dim3(256), dim3(512), 0, stream>>>(xf, c2);
    k_pass2 <<<dim3(256), dim3(512), 0, stream>>>(xf, xt, c2, x, gamma, out);
}